// Round 13
// baseline (133.347 us; speedup 1.0000x reference)
//
#include <hip/hip_runtime.h>
#include <hip/hip_bf16.h>
#include <stdint.h>

// Fused attention block: S=2048, B=2, D=1024, H=16, HD=64.
// Round 13: (a) flash = R12 loop VERBATIM + KV-split x2 via global partials
// (grid 1024 -> 4 blocks/CU, 4 waves/SIMD; R7's validated dump+reduce pair);
// (b) xcvt + 3 weight transposes fused into one prep kernel.

typedef __bf16 bf16_t;
typedef __bf16 bf16x8 __attribute__((ext_vector_type(8)));
typedef __bf16 bf16x4 __attribute__((ext_vector_type(4)));
typedef __bf16 bf16x2 __attribute__((ext_vector_type(2)));
typedef float f32x4 __attribute__((ext_vector_type(4)));
typedef float f32x16 __attribute__((ext_vector_type(16)));
typedef uint32_t u32;

#define S_LEN 2048
#define BATCH 2
#define DMODEL 1024
#define NHEAD 16
#define HDIM 64
#define KVB 64
#define HITER 16               // KV tiles per half (split x2)
// 0.125 (1/sqrt(64)) * log2(e), folded into Q so softmax uses exp2
#define Q_SCALE 0.1803368801111204f

__device__ inline void gld16(const void* g, void* l)
{
    __builtin_amdgcn_global_load_lds(
        (const __attribute__((address_space(1))) void*)g,
        (__attribute__((address_space(3))) void*)l, 16, 0, 0);
}

__device__ inline u32 pack2(float a, float b)
{
    union { bf16x2 h; u32 u; } c;
    c.h[0] = (bf16_t)a; c.h[1] = (bf16_t)b;
    return c.u;
}

// ---------------------------------------------------------------------------
// Fused prep: blocks [0,2048) = X f32->bf16; [2048,2560) = Wkv transpose;
// [2560,2816) = Wq transpose; [2816,3072) = Wp transpose.
// ---------------------------------------------------------------------------
__global__ __launch_bounds__(256) void prep_kernel(
    const float* __restrict__ X, bf16_t* __restrict__ Xbf,
    const float* __restrict__ Wkv, const float* __restrict__ Wq,
    const float* __restrict__ Wp, bf16_t* __restrict__ WqkvT,
    bf16_t* __restrict__ WpT)
{
    __shared__ float tile[64][65];
    int bid = blockIdx.x;
    if (bid < 2048) {
        size_t i = ((size_t)bid * 256 + threadIdx.x) * 8;
        float4 f0 = *(const float4*)(X + i);
        float4 f1 = *(const float4*)(X + i + 4);
        bf16x8 o;
        o[0] = (bf16_t)f0.x; o[1] = (bf16_t)f0.y;
        o[2] = (bf16_t)f0.z; o[3] = (bf16_t)f0.w;
        o[4] = (bf16_t)f1.x; o[5] = (bf16_t)f1.y;
        o[6] = (bf16_t)f1.z; o[7] = (bf16_t)f1.w;
        *(bf16x8*)(Xbf + i) = o;
        return;
    }
    const float* in;
    bf16_t* out;
    int N, n0, k0;
    const int K = 1024;
    if (bid < 2560) {
        int id = bid - 2048;            // 32 x 16
        in = Wkv; out = WqkvT; N = 2048;
        n0 = (id & 31) * 64; k0 = (id >> 5) * 64;
    } else if (bid < 2816) {
        int id = bid - 2560;            // 16 x 16
        in = Wq; out = WqkvT + (size_t)2048 * 1024; N = 1024;
        n0 = (id & 15) * 64; k0 = (id >> 4) * 64;
    } else {
        int id = bid - 2816;            // 16 x 16
        in = Wp; out = WpT; N = 1024;
        n0 = (id & 15) * 64; k0 = (id >> 4) * 64;
    }
    int r = threadIdx.x >> 2;
    int c = (threadIdx.x & 3) * 16;
    const float* src = in + (size_t)(k0 + r) * N + n0 + c;
#pragma unroll
    for (int j = 0; j < 16; j += 4) {
        float4 f = *(const float4*)(src + j);
        tile[r][c + j + 0] = f.x;
        tile[r][c + j + 1] = f.y;
        tile[r][c + j + 2] = f.z;
        tile[r][c + j + 3] = f.w;
    }
    __syncthreads();
    bf16x8 o0, o1;
#pragma unroll
    for (int j = 0; j < 8; ++j) o0[j] = (bf16_t)tile[c + j][r];
#pragma unroll
    for (int j = 0; j < 8; ++j) o1[j] = (bf16_t)tile[c + 8 + j][r];
    bf16_t* dst = out + (size_t)(n0 + r) * K + k0 + c;
    *(bf16x8*)dst = o0;
    *(bf16x8*)(dst + 8) = o1;
}

// ---------------------------------------------------------------------------
// Fused QKV GEMM, BK=64, XOR-swizzled gload_lds staging (R12 verbatim).
// ---------------------------------------------------------------------------
__global__ __launch_bounds__(256) void gemm_qkv(
    const bf16_t* __restrict__ A, const bf16_t* __restrict__ WT,
    const float* __restrict__ bkv, const float* __restrict__ bq,
    bf16_t* __restrict__ outK, bf16_t* __restrict__ outV,
    bf16_t* __restrict__ outQ)
{
    const int K = 1024;
    __shared__ __align__(16) char AsB[128 * 128];
    __shared__ __align__(16) char BsB[128 * 128];
    int tid = threadIdx.x;
    int wave = tid >> 6, lane = tid & 63;
    int l15 = lane & 15, l4 = lane >> 4;
    int m0 = blockIdx.x * 128, n0 = blockIdx.y * 128;
    int wr = (wave >> 1) * 64, wc = (wave & 1) * 64;

    char* ldsT = (wave < 2) ? AsB : BsB;
    const bf16_t* gbase = (wave < 2) ? A : WT;
    int rbase = (wave & 1) * 64;
    int tile0 = (wave < 2) ? m0 : n0;
    int srow = lane >> 3;
    int kcb = ((lane & 7) << 4) ^ (srow << 4);
    int rx = (l15 & 7) << 4;

    f32x4 acc[4][4] = {};

    for (int k0 = 0; k0 < K; k0 += 64) {
#pragma unroll
        for (int j = 0; j < 8; ++j) {
            const char* g = (const char*)(gbase +
                (size_t)(tile0 + rbase + j * 8 + srow) * K + k0) + kcb;
            gld16(g, ldsT + (rbase + j * 8) * 128);
        }
        __syncthreads();
#pragma unroll
        for (int kk = 0; kk < 2; ++kk) {
            int cb = (kk * 64 + l4 * 16) ^ rx;
            bf16x8 af[4], bfr[4];
#pragma unroll
            for (int i = 0; i < 4; ++i)
                af[i] = *(const bf16x8*)(AsB + (wr + i * 16 + l15) * 128 + cb);
#pragma unroll
            for (int i = 0; i < 4; ++i)
                bfr[i] = *(const bf16x8*)(BsB + (wc + i * 16 + l15) * 128 + cb);
#pragma unroll
            for (int mi = 0; mi < 4; ++mi)
#pragma unroll
                for (int ni = 0; ni < 4; ++ni)
                    acc[mi][ni] = __builtin_amdgcn_mfma_f32_16x16x32_bf16(
                        af[mi], bfr[ni], acc[mi][ni], 0, 0, 0);
        }
        __syncthreads();
    }

#pragma unroll
    for (int mi = 0; mi < 4; ++mi) {
#pragma unroll
        for (int ni = 0; ni < 4; ++ni) {
#pragma unroll
            for (int e = 0; e < 4; ++e) {
                int gm = m0 + wr + mi * 16 + l4 * 4 + e;
                int gn = n0 + wc + ni * 16 + l15;
                float bsel = (gn < 2048) ? bkv[gn] : bq[gn - 2048];
                float v = acc[mi][ni][e] + bsel;
                int s = gm >> 1, b = gm & 1;
                int nn = gn & 1023;
                int h = nn >> 6, d = nn & 63;
                size_t idx = ((size_t)((b << 4) + h) * S_LEN + s) * HDIM + d;
                if (gn < 1024)
                    outK[idx] = (bf16_t)v;
                else if (gn < 2048)
                    outV[idx] = (bf16_t)v;
                else
                    outQ[idx] = (bf16_t)(v * Q_SCALE);
            }
        }
    }
}

// ---------------------------------------------------------------------------
// Output projection GEMM, BK=64, XOR-swizzled staging (R12 verbatim).
// ---------------------------------------------------------------------------
__global__ __launch_bounds__(256) void gemm_out_kernel(
    const bf16_t* __restrict__ A, const bf16_t* __restrict__ WT,
    const float* __restrict__ bias, float* __restrict__ outF)
{
    const int K = 1024, N = 1024;
    __shared__ __align__(16) char AsB[64 * 128];
    __shared__ __align__(16) char BsB[128 * 128];
    int tid = threadIdx.x, wave = tid >> 6, lane = tid & 63;
    int l15 = lane & 15, l4 = lane >> 4;
    int m0 = blockIdx.x * 64, n0 = blockIdx.y * 128;
    int wc = wave * 32;
    int srow = lane >> 3;
    int kcb = ((lane & 7) << 4) ^ (srow << 4);
    int rx = (l15 & 7) << 4;

    f32x4 acc[4][2] = {};

    for (int k0 = 0; k0 < K; k0 += 64) {
#pragma unroll
        for (int j = 0; j < 6; ++j) {
            int slot = wave * 6 + j;
            const bf16_t* g;
            char* l;
            if (slot < 8) {
                g = A + (size_t)(m0 + slot * 8 + srow) * K + k0;
                l = AsB + slot * 1024;
            } else {
                g = WT + (size_t)(n0 + (slot - 8) * 8 + srow) * K + k0;
                l = BsB + (slot - 8) * 1024;
            }
            gld16((const char*)g + kcb, l);
        }
        __syncthreads();
#pragma unroll
        for (int kk = 0; kk < 2; ++kk) {
            int cb = (kk * 64 + l4 * 16) ^ rx;
            bf16x8 af[4], bfr[2];
#pragma unroll
            for (int i = 0; i < 4; ++i)
                af[i] = *(const bf16x8*)(AsB + (i * 16 + l15) * 128 + cb);
#pragma unroll
            for (int i = 0; i < 2; ++i)
                bfr[i] = *(const bf16x8*)(BsB + (wc + i * 16 + l15) * 128 + cb);
#pragma unroll
            for (int mi = 0; mi < 4; ++mi)
#pragma unroll
                for (int ni = 0; ni < 2; ++ni)
                    acc[mi][ni] = __builtin_amdgcn_mfma_f32_16x16x32_bf16(
                        af[mi], bfr[ni], acc[mi][ni], 0, 0, 0);
        }
        __syncthreads();
    }

#pragma unroll
    for (int mi = 0; mi < 4; ++mi)
#pragma unroll
        for (int ni = 0; ni < 2; ++ni)
#pragma unroll
            for (int e = 0; e < 4; ++e) {
                int gm = m0 + mi * 16 + l4 * 4 + e;
                int gn = n0 + wc + ni * 16 + l15;
                outF[(size_t)gm * N + gn] = acc[mi][ni][e] + bias[gn];
            }
}

// ---------------------------------------------------------------------------
// Flash attention: R12 loop verbatim, KV-split x2 via global partials.
// Grid 1024 = 32 bh x 16 qx x 2 halves (XCD-chunked). Half h does tiles
// [h*16, h*16+16); epilogue dumps raw acc + l (exact sums, max-free softmax).
// ---------------------------------------------------------------------------
__global__ __launch_bounds__(256) void flash_kernel(
    const bf16_t* __restrict__ Qb, const bf16_t* __restrict__ Kb,
    const bf16_t* __restrict__ Vb, float* __restrict__ Opart,
    float* __restrict__ Lpart)
{
    __shared__ __align__(16) char lds[34816];
    char* KsB = lds;                         // 2 x [64][64] bf16, swizzled
    bf16_t* VtB = (bf16_t*)(lds + 16384);    // 2 x [64][72] bf16

    int bid = blockIdx.x;
    int id = (bid & 7) * 128 + (bid >> 3);   // XCD-chunked
    int bh = id >> 5;
    int qx = (id >> 1) & 15;
    int half = id & 1;

    int tid = threadIdx.x, wave = tid >> 6, lane = tid & 63;
    int l31 = lane & 31, hi = lane >> 5;

    const bf16_t* Qp = Qb + (size_t)bh * S_LEN * HDIM;
    const bf16_t* Kp = Kb + (size_t)bh * S_LEN * HDIM;
    const bf16_t* Vp = Vb + (size_t)bh * S_LEN * HDIM;

    int q0 = qx * 128 + wave * 32;

    bf16x8 qf[4];
#pragma unroll
    for (int dc = 0; dc < 4; ++dc)
        qf[dc] = *(const bf16x8*)(Qp + (size_t)(q0 + l31) * HDIM + dc * 16 + hi * 8);

    f32x16 acc0 = {}, acc1 = {};
    float l_run = 0.f;

    int krow = lane >> 3;
    int kcb = ((lane & 7) << 4) ^ (krow << 4);
    int vd = (tid >> 4) * 4;
    int vt = (tid & 15) * 2;
    bf16x4 vreg[2][2];
    int swz = (l31 & 7) << 4;

#define STAGE_K(it, buf)                                                       \
    {                                                                          \
        _Pragma("unroll")                                                      \
        for (int j = 0; j < 2; ++j) {                                          \
            int t = wave * 16 + j * 8 + krow;                                  \
            const char* g = (const char*)Kp +                                  \
                ((size_t)((it) * KVB + t) * HDIM) * 2 + kcb;                   \
            gld16(g, KsB + (buf) * 8192 + (wave * 16 + j * 8) * 128);          \
        }                                                                      \
    }
#define LOAD_V(it)                                                             \
    {                                                                          \
        const bf16_t* vb = Vp + (size_t)((it) * KVB + vt) * HDIM + vd;         \
        vreg[0][0] = *(const bf16x4*)vb;                                       \
        vreg[0][1] = *(const bf16x4*)(vb + HDIM);                              \
        vreg[1][0] = *(const bf16x4*)(vb + 32 * HDIM);                         \
        vreg[1][1] = *(const bf16x4*)(vb + 33 * HDIM);                         \
    }
#define WRITE_V(buf)                                                           \
    {                                                                          \
        bf16_t* vtb = VtB + (buf) * 4608;                                      \
        _Pragma("unroll")                                                      \
        for (int p = 0; p < 2; ++p) {                                          \
            _Pragma("unroll")                                                  \
            for (int j = 0; j < 4; ++j) {                                      \
                bf16x2 w;                                                      \
                w[0] = vreg[p][0][j];                                          \
                w[1] = vreg[p][1][j];                                          \
                *(bf16x2*)&vtb[(vd + j) * 72 + vt + 32 * p] = w;               \
            }                                                                  \
        }                                                                      \
    }

    STAGE_K(half * HITER, 0);
    LOAD_V(half * HITER);
    WRITE_V(0);
    __syncthreads();

    for (int i = 0; i < HITER; ++i) {
        int cur = i & 1;
        int it = half * HITER + i;
        if (i + 1 < HITER) {
            STAGE_K(it + 1, cur ^ 1);
            LOAD_V(it + 1);
        }

        // ---- QK^T (S^T)
        f32x16 s0 = {}, s1 = {};
        __builtin_amdgcn_s_setprio(1);
#pragma unroll
        for (int dc = 0; dc < 4; ++dc) {
            bf16x8 k0 = *(const bf16x8*)(KsB + cur * 8192 + l31 * 128 +
                                         ((dc * 32 + hi * 16) ^ swz));
            bf16x8 k1 = *(const bf16x8*)(KsB + cur * 8192 + (32 + l31) * 128 +
                                         ((dc * 32 + hi * 16) ^ swz));
            s0 = __builtin_amdgcn_mfma_f32_32x32x16_bf16(k0, qf[dc], s0, 0, 0, 0);
            s1 = __builtin_amdgcn_mfma_f32_32x32x16_bf16(k1, qf[dc], s1, 0, 0, 0);
        }
        __builtin_amdgcn_s_setprio(0);

        // ---- max-free softmax: p = exp2(s); l += sum(p)
#pragma unroll
        for (int r = 0; r < 16; ++r) s0[r] = __builtin_amdgcn_exp2f(s0[r]);
#pragma unroll
        for (int r = 0; r < 16; ++r) s1[r] = __builtin_amdgcn_exp2f(s1[r]);
        float a8[8];
#pragma unroll
        for (int r = 0; r < 8; ++r)
            a8[r] = (s0[r] + s0[r + 8]) + (s1[r] + s1[r + 8]);
        float rs = ((a8[0] + a8[1]) + (a8[2] + a8[3])) +
                   ((a8[4] + a8[5]) + (a8[6] + a8[7]));
        rs += __shfl_xor(rs, 32);             // cross-half combine
        l_run += rs;

        // ---- P exchange (permlane32_swap, distinct operands) + PV
        __builtin_amdgcn_s_setprio(1);
#pragma unroll
        for (int s = 0; s < 4; ++s) {
            const int base = 8 * (s & 1);
            f32x16& P = (s < 2) ? s0 : s1;
            u32 a0 = pack2(P[base + 0], P[base + 1]);
            u32 a1 = pack2(P[base + 2], P[base + 3]);
            u32 b0 = pack2(P[base + 4], P[base + 5]);
            u32 b1 = pack2(P[base + 6], P[base + 7]);
            asm("v_permlane32_swap_b32 %0, %1" : "+v"(a0), "+v"(b0));
            asm("v_permlane32_swap_b32 %0, %1" : "+v"(a1), "+v"(b1));
            union { u32 u[4]; bf16x8 v; } pa;
            pa.u[0] = a0; pa.u[1] = a1; pa.u[2] = b0; pa.u[3] = b1;
            const bf16_t* vtb = VtB + cur * 4608;
            bf16x8 va0 = *(const bf16x8*)&vtb[l31 * 72 + s * 16 + hi * 8];
            bf16x8 va1 = *(const bf16x8*)&vtb[(32 + l31) * 72 + s * 16 + hi * 8];
            acc0 = __builtin_amdgcn_mfma_f32_32x32x16_bf16(va0, pa.v, acc0, 0, 0, 0);
            acc1 = __builtin_amdgcn_mfma_f32_32x32x16_bf16(va1, pa.v, acc1, 0, 0, 0);
        }
        __builtin_amdgcn_s_setprio(0);

        if (i + 1 < HITER) WRITE_V(cur ^ 1);
        __syncthreads();
    }

    // ---- dump raw partial: [T*2+half][8 quads][64 lanes][4 f32]
    int T = (bh * 16 + qx) * 4 + wave;
    float* op = Opart + ((size_t)T * 2 + half) * 2048;
#pragma unroll
    for (int g = 0; g < 4; ++g) {
        f32x4 w0, w1;
#pragma unroll
        for (int e = 0; e < 4; ++e) { w0[e] = acc0[4 * g + e]; w1[e] = acc1[4 * g + e]; }
        *(f32x4*)(op + g * 256 + lane * 4) = w0;
        *(f32x4*)(op + (g + 4) * 256 + lane * 4) = w1;
    }
    if (lane < 32) Lpart[((size_t)T * 2 + half) * 32 + lane] = l_run;
}

// ---------------------------------------------------------------------------
// Reduce: sum 2 KV-half partials, normalize, transpose, write AVb bf16.
// (R7 kernel, validated passing in R7-R9.)
// ---------------------------------------------------------------------------
__global__ __launch_bounds__(256) void reduce_kernel(
    const float* __restrict__ Opart, const float* __restrict__ Lpart,
    bf16_t* __restrict__ AVb)
{
    __shared__ bf16_t sw_all[4][32 * 72];
    int tid = threadIdx.x, wave = tid >> 6, lane = tid & 63;
    int l31 = lane & 31, hi = lane >> 5;
    int T = blockIdx.x * 4 + wave;
    int bh = T >> 6, qx = (T >> 2) & 15, wv = T & 3;
    int q0 = qx * 128 + wv * 32;

    const float* o0 = Opart + (size_t)T * 2 * 2048;
    const float* o1 = o0 + 2048;
    float lsum = Lpart[(size_t)T * 2 * 32 + l31] +
                 Lpart[((size_t)T * 2 + 1) * 32 + l31];
    float inv = 1.0f / lsum;

    bf16_t* sw = sw_all[wave];
#pragma unroll
    for (int g = 0; g < 4; ++g) {
        f32x4 a0 = *(const f32x4*)(o0 + g * 256 + lane * 4);
        f32x4 b0 = *(const f32x4*)(o1 + g * 256 + lane * 4);
        f32x4 a1 = *(const f32x4*)(o0 + (g + 4) * 256 + lane * 4);
        f32x4 b1 = *(const f32x4*)(o1 + (g + 4) * 256 + lane * 4);
        bf16x4 w0, w1;
#pragma unroll
        for (int e = 0; e < 4; ++e) {
            w0[e] = (bf16_t)((a0[e] + b0[e]) * inv);
            w1[e] = (bf16_t)((a1[e] + b1[e]) * inv);
        }
        int d0 = 8 * g + 4 * hi;
        *(bf16x4*)&sw[l31 * 72 + d0] = w0;
        *(bf16x4*)&sw[l31 * 72 + 32 + d0] = w1;
    }
    __syncthreads();
    {
        int q = lane >> 1, hf = lane & 1;
        const bf16_t* srow = sw + q * 72 + hf * 32;
        int s = q0 + q;
        int b = bh >> 4, h = bh & 15;
        bf16_t* dst = AVb + ((size_t)s * BATCH + b) * DMODEL + h * HDIM + hf * 32;
#pragma unroll
        for (int k = 0; k < 4; ++k)
            *(bf16x8*)(dst + k * 8) = *(const bf16x8*)(srow + k * 8);
    }
}

// ---------------------------------------------------------------------------
extern "C" void kernel_launch(void* const* d_in, const int* in_sizes, int n_in,
                              void* d_out, int out_size, void* d_ws, size_t ws_size,
                              hipStream_t stream)
{
    const float* X   = (const float*)d_in[0];
    const float* Wkv = (const float*)d_in[1];
    const float* bkv = (const float*)d_in[2];
    const float* Wq  = (const float*)d_in[3];
    const float* bq  = (const float*)d_in[4];
    const float* Wp  = (const float*)d_in[5];
    const float* bp  = (const float*)d_in[6];
    float* out = (float*)d_out;

    char* ws = (char*)d_ws;
    size_t off = 0;
    auto alloc = [&](size_t bytes) -> void* {
        void* p = ws + off;
        off += (bytes + 255) & ~(size_t)255;
        return p;
    };
    bf16_t* WqkvT = (bf16_t*)alloc((size_t)3072 * 1024 * 2);  // [Wkv^T ; Wq^T]
    bf16_t* WpT   = (bf16_t*)alloc((size_t)1024 * 1024 * 2);
    bf16_t* Qb    = (bf16_t*)alloc((size_t)32 * S_LEN * HDIM * 2);
    bf16_t* Kb    = (bf16_t*)alloc((size_t)32 * S_LEN * HDIM * 2);
    bf16_t* Vb    = (bf16_t*)alloc((size_t)32 * S_LEN * HDIM * 2);
    bf16_t* AVb   = (bf16_t*)alloc((size_t)4096 * 1024 * 2);
    float*  Opart = (float*)alloc((size_t)2048 * 2 * 2048 * 4);  // 32 MB
    float*  Lpart = (float*)alloc((size_t)2048 * 2 * 32 * 4);
    // Xbf aliases Opart: Xbf dead before flash writes partials (stream order;
    // validated in R7-R9 runs)
    bf16_t* Xbf   = (bf16_t*)Opart;

    prep_kernel<<<3072, 256, 0, stream>>>(X, Xbf, Wkv, Wq, Wp, WqkvT, WpT);
    gemm_qkv<<<dim3(32, 24), 256, 0, stream>>>(Xbf, WqkvT, bkv, bq, Kb, Vb, Qb);
    flash_kernel<<<1024, 256, 0, stream>>>(Qb, Kb, Vb, Opart, Lpart);
    reduce_kernel<<<512, 256, 0, stream>>>(Opart, Lpart, AVb);
    gemm_out_kernel<<<dim3(64, 8), 256, 0, stream>>>(AVb, WpT, bp, out);
}

// Round 14
// 122.702 us; speedup vs baseline: 1.0868x; 1.0868x over previous
//
#include <hip/hip_runtime.h>
#include <hip/hip_bf16.h>
#include <stdint.h>

// Fused attention block: S=2048, B=2, D=1024, H=16, HD=64.
// Round 14: R12 verbatim (best GEMMs + best flash) + R13's fused prep kernel.
// Flash occupancy is register-capped (VGPR+AGPR ~160/wave -> 2 blocks/CU);
// KV-splits don't help (R13). Flash frozen at ~60us.

typedef __bf16 bf16_t;
typedef __bf16 bf16x8 __attribute__((ext_vector_type(8)));
typedef __bf16 bf16x4 __attribute__((ext_vector_type(4)));
typedef __bf16 bf16x2 __attribute__((ext_vector_type(2)));
typedef float f32x4 __attribute__((ext_vector_type(4)));
typedef float f32x16 __attribute__((ext_vector_type(16)));
typedef uint32_t u32;

#define S_LEN 2048
#define BATCH 2
#define DMODEL 1024
#define NHEAD 16
#define HDIM 64
#define KVB 64
#define FNT (S_LEN / KVB)
// 0.125 (1/sqrt(64)) * log2(e), folded into Q so softmax uses exp2
#define Q_SCALE 0.1803368801111204f

__device__ inline void gld16(const void* g, void* l)
{
    __builtin_amdgcn_global_load_lds(
        (const __attribute__((address_space(1))) void*)g,
        (__attribute__((address_space(3))) void*)l, 16, 0, 0);
}

__device__ inline u32 pack2(float a, float b)
{
    union { bf16x2 h; u32 u; } c;
    c.h[0] = (bf16_t)a; c.h[1] = (bf16_t)b;
    return c.u;
}

// ---------------------------------------------------------------------------
// Fused prep: blocks [0,2048) = X f32->bf16; [2048,2560) = Wkv transpose;
// [2560,2816) = Wq transpose; [2816,3072) = Wp transpose.
// ---------------------------------------------------------------------------
__global__ __launch_bounds__(256) void prep_kernel(
    const float* __restrict__ X, bf16_t* __restrict__ Xbf,
    const float* __restrict__ Wkv, const float* __restrict__ Wq,
    const float* __restrict__ Wp, bf16_t* __restrict__ WqkvT,
    bf16_t* __restrict__ WpT)
{
    __shared__ float tile[64][65];
    int bid = blockIdx.x;
    if (bid < 2048) {
        size_t i = ((size_t)bid * 256 + threadIdx.x) * 8;
        float4 f0 = *(const float4*)(X + i);
        float4 f1 = *(const float4*)(X + i + 4);
        bf16x8 o;
        o[0] = (bf16_t)f0.x; o[1] = (bf16_t)f0.y;
        o[2] = (bf16_t)f0.z; o[3] = (bf16_t)f0.w;
        o[4] = (bf16_t)f1.x; o[5] = (bf16_t)f1.y;
        o[6] = (bf16_t)f1.z; o[7] = (bf16_t)f1.w;
        *(bf16x8*)(Xbf + i) = o;
        return;
    }
    const float* in;
    bf16_t* out;
    int N, n0, k0;
    const int K = 1024;
    if (bid < 2560) {
        int id = bid - 2048;            // 32 x 16
        in = Wkv; out = WqkvT; N = 2048;
        n0 = (id & 31) * 64; k0 = (id >> 5) * 64;
    } else if (bid < 2816) {
        int id = bid - 2560;            // 16 x 16
        in = Wq; out = WqkvT + (size_t)2048 * 1024; N = 1024;
        n0 = (id & 15) * 64; k0 = (id >> 4) * 64;
    } else {
        int id = bid - 2816;            // 16 x 16
        in = Wp; out = WpT; N = 1024;
        n0 = (id & 15) * 64; k0 = (id >> 4) * 64;
    }
    int r = threadIdx.x >> 2;
    int c = (threadIdx.x & 3) * 16;
    const float* src = in + (size_t)(k0 + r) * N + n0 + c;
#pragma unroll
    for (int j = 0; j < 16; j += 4) {
        float4 f = *(const float4*)(src + j);
        tile[r][c + j + 0] = f.x;
        tile[r][c + j + 1] = f.y;
        tile[r][c + j + 2] = f.z;
        tile[r][c + j + 3] = f.w;
    }
    __syncthreads();
    bf16x8 o0, o1;
#pragma unroll
    for (int j = 0; j < 8; ++j) o0[j] = (bf16_t)tile[c + j][r];
#pragma unroll
    for (int j = 0; j < 8; ++j) o1[j] = (bf16_t)tile[c + 8 + j][r];
    bf16_t* dst = out + (size_t)(n0 + r) * K + k0 + c;
    *(bf16x8*)dst = o0;
    *(bf16x8*)(dst + 8) = o1;
}

// ---------------------------------------------------------------------------
// Fused QKV GEMM, BK=64, XOR-swizzled gload_lds staging (R12 verbatim).
// ---------------------------------------------------------------------------
__global__ __launch_bounds__(256) void gemm_qkv(
    const bf16_t* __restrict__ A, const bf16_t* __restrict__ WT,
    const float* __restrict__ bkv, const float* __restrict__ bq,
    bf16_t* __restrict__ outK, bf16_t* __restrict__ outV,
    bf16_t* __restrict__ outQ)
{
    const int K = 1024;
    __shared__ __align__(16) char AsB[128 * 128];
    __shared__ __align__(16) char BsB[128 * 128];
    int tid = threadIdx.x;
    int wave = tid >> 6, lane = tid & 63;
    int l15 = lane & 15, l4 = lane >> 4;
    int m0 = blockIdx.x * 128, n0 = blockIdx.y * 128;
    int wr = (wave >> 1) * 64, wc = (wave & 1) * 64;

    char* ldsT = (wave < 2) ? AsB : BsB;
    const bf16_t* gbase = (wave < 2) ? A : WT;
    int rbase = (wave & 1) * 64;
    int tile0 = (wave < 2) ? m0 : n0;
    int srow = lane >> 3;
    int kcb = ((lane & 7) << 4) ^ (srow << 4);
    int rx = (l15 & 7) << 4;

    f32x4 acc[4][4] = {};

    for (int k0 = 0; k0 < K; k0 += 64) {
#pragma unroll
        for (int j = 0; j < 8; ++j) {
            const char* g = (const char*)(gbase +
                (size_t)(tile0 + rbase + j * 8 + srow) * K + k0) + kcb;
            gld16(g, ldsT + (rbase + j * 8) * 128);
        }
        __syncthreads();
#pragma unroll
        for (int kk = 0; kk < 2; ++kk) {
            int cb = (kk * 64 + l4 * 16) ^ rx;
            bf16x8 af[4], bfr[4];
#pragma unroll
            for (int i = 0; i < 4; ++i)
                af[i] = *(const bf16x8*)(AsB + (wr + i * 16 + l15) * 128 + cb);
#pragma unroll
            for (int i = 0; i < 4; ++i)
                bfr[i] = *(const bf16x8*)(BsB + (wc + i * 16 + l15) * 128 + cb);
#pragma unroll
            for (int mi = 0; mi < 4; ++mi)
#pragma unroll
                for (int ni = 0; ni < 4; ++ni)
                    acc[mi][ni] = __builtin_amdgcn_mfma_f32_16x16x32_bf16(
                        af[mi], bfr[ni], acc[mi][ni], 0, 0, 0);
        }
        __syncthreads();
    }

#pragma unroll
    for (int mi = 0; mi < 4; ++mi) {
#pragma unroll
        for (int ni = 0; ni < 4; ++ni) {
#pragma unroll
            for (int e = 0; e < 4; ++e) {
                int gm = m0 + wr + mi * 16 + l4 * 4 + e;
                int gn = n0 + wc + ni * 16 + l15;
                float bsel = (gn < 2048) ? bkv[gn] : bq[gn - 2048];
                float v = acc[mi][ni][e] + bsel;
                int s = gm >> 1, b = gm & 1;
                int nn = gn & 1023;
                int h = nn >> 6, d = nn & 63;
                size_t idx = ((size_t)((b << 4) + h) * S_LEN + s) * HDIM + d;
                if (gn < 1024)
                    outK[idx] = (bf16_t)v;
                else if (gn < 2048)
                    outV[idx] = (bf16_t)v;
                else
                    outQ[idx] = (bf16_t)(v * Q_SCALE);
            }
        }
    }
}

// ---------------------------------------------------------------------------
// Output projection GEMM, BK=64, XOR-swizzled staging (R12 verbatim).
// ---------------------------------------------------------------------------
__global__ __launch_bounds__(256) void gemm_out_kernel(
    const bf16_t* __restrict__ A, const bf16_t* __restrict__ WT,
    const float* __restrict__ bias, float* __restrict__ outF)
{
    const int K = 1024, N = 1024;
    __shared__ __align__(16) char AsB[64 * 128];
    __shared__ __align__(16) char BsB[128 * 128];
    int tid = threadIdx.x, wave = tid >> 6, lane = tid & 63;
    int l15 = lane & 15, l4 = lane >> 4;
    int m0 = blockIdx.x * 64, n0 = blockIdx.y * 128;
    int wc = wave * 32;
    int srow = lane >> 3;
    int kcb = ((lane & 7) << 4) ^ (srow << 4);
    int rx = (l15 & 7) << 4;

    f32x4 acc[4][2] = {};

    for (int k0 = 0; k0 < K; k0 += 64) {
#pragma unroll
        for (int j = 0; j < 6; ++j) {
            int slot = wave * 6 + j;
            const bf16_t* g;
            char* l;
            if (slot < 8) {
                g = A + (size_t)(m0 + slot * 8 + srow) * K + k0;
                l = AsB + slot * 1024;
            } else {
                g = WT + (size_t)(n0 + (slot - 8) * 8 + srow) * K + k0;
                l = BsB + (slot - 8) * 1024;
            }
            gld16((const char*)g + kcb, l);
        }
        __syncthreads();
#pragma unroll
        for (int kk = 0; kk < 2; ++kk) {
            int cb = (kk * 64 + l4 * 16) ^ rx;
            bf16x8 af[4], bfr[2];
#pragma unroll
            for (int i = 0; i < 4; ++i)
                af[i] = *(const bf16x8*)(AsB + (i * 16 + l15) * 128 + cb);
#pragma unroll
            for (int i = 0; i < 2; ++i)
                bfr[i] = *(const bf16x8*)(BsB + (wc + i * 16 + l15) * 128 + cb);
#pragma unroll
            for (int mi = 0; mi < 4; ++mi)
#pragma unroll
                for (int ni = 0; ni < 2; ++ni)
                    acc[mi][ni] = __builtin_amdgcn_mfma_f32_16x16x32_bf16(
                        af[mi], bfr[ni], acc[mi][ni], 0, 0, 0);
        }
        __syncthreads();
    }

#pragma unroll
    for (int mi = 0; mi < 4; ++mi)
#pragma unroll
        for (int ni = 0; ni < 2; ++ni)
#pragma unroll
            for (int e = 0; e < 4; ++e) {
                int gm = m0 + mi * 16 + l4 * 4 + e;
                int gn = n0 + wc + ni * 16 + l15;
                outF[(size_t)gm * N + gn] = acc[mi][ni][e] + bias[gn];
            }
}

// ---------------------------------------------------------------------------
// Flash attention (R12/R10 verbatim): swapped-QK^T 32x32, gload_lds K + XOR
// swizzle, reg-staged V, max-free softmax, permlane32_swap P-exchange.
// ---------------------------------------------------------------------------
__global__ __launch_bounds__(256) void flash_kernel(
    const bf16_t* __restrict__ Qb, const bf16_t* __restrict__ Kb,
    const bf16_t* __restrict__ Vb, bf16_t* __restrict__ AVb)
{
    __shared__ __align__(16) char lds[34816];
    char* KsB = lds;                         // 2 x [64][64] bf16, swizzled
    bf16_t* VtB = (bf16_t*)(lds + 16384);    // 2 x [64][72] bf16

    int bh = blockIdx.y;
    int tid = threadIdx.x, wave = tid >> 6, lane = tid & 63;
    int l31 = lane & 31, hi = lane >> 5;

    const bf16_t* Qp = Qb + (size_t)bh * S_LEN * HDIM;
    const bf16_t* Kp = Kb + (size_t)bh * S_LEN * HDIM;
    const bf16_t* Vp = Vb + (size_t)bh * S_LEN * HDIM;

    int q0 = blockIdx.x * 128 + wave * 32;

    bf16x8 qf[4];
#pragma unroll
    for (int dc = 0; dc < 4; ++dc)
        qf[dc] = *(const bf16x8*)(Qp + (size_t)(q0 + l31) * HDIM + dc * 16 + hi * 8);

    f32x16 acc0 = {}, acc1 = {};
    float l_run = 0.f;

    int krow = lane >> 3;
    int kcb = ((lane & 7) << 4) ^ (krow << 4);
    int vd = (tid >> 4) * 4;
    int vt = (tid & 15) * 2;
    bf16x4 vreg[2][2];
    int swz = (l31 & 7) << 4;

#define STAGE_K(it, buf)                                                       \
    {                                                                          \
        _Pragma("unroll")                                                      \
        for (int j = 0; j < 2; ++j) {                                          \
            int t = wave * 16 + j * 8 + krow;                                  \
            const char* g = (const char*)Kp +                                  \
                ((size_t)((it) * KVB + t) * HDIM) * 2 + kcb;                   \
            gld16(g, KsB + (buf) * 8192 + (wave * 16 + j * 8) * 128);          \
        }                                                                      \
    }
#define LOAD_V(it)                                                             \
    {                                                                          \
        const bf16_t* vb = Vp + (size_t)((it) * KVB + vt) * HDIM + vd;         \
        vreg[0][0] = *(const bf16x4*)vb;                                       \
        vreg[0][1] = *(const bf16x4*)(vb + HDIM);                              \
        vreg[1][0] = *(const bf16x4*)(vb + 32 * HDIM);                         \
        vreg[1][1] = *(const bf16x4*)(vb + 33 * HDIM);                         \
    }
#define WRITE_V(buf)                                                           \
    {                                                                          \
        bf16_t* vtb = VtB + (buf) * 4608;                                      \
        _Pragma("unroll")                                                      \
        for (int p = 0; p < 2; ++p) {                                          \
            _Pragma("unroll")                                                  \
            for (int j = 0; j < 4; ++j) {                                      \
                bf16x2 w;                                                      \
                w[0] = vreg[p][0][j];                                          \
                w[1] = vreg[p][1][j];                                          \
                *(bf16x2*)&vtb[(vd + j) * 72 + vt + 32 * p] = w;               \
            }                                                                  \
        }                                                                      \
    }

    STAGE_K(0, 0);
    LOAD_V(0);
    WRITE_V(0);
    __syncthreads();

    for (int it = 0; it < FNT; ++it) {
        int cur = it & 1;
        if (it + 1 < FNT) {
            STAGE_K(it + 1, cur ^ 1);
            LOAD_V(it + 1);
        }

        // ---- QK^T (S^T)
        f32x16 s0 = {}, s1 = {};
        __builtin_amdgcn_s_setprio(1);
#pragma unroll
        for (int dc = 0; dc < 4; ++dc) {
            bf16x8 k0 = *(const bf16x8*)(KsB + cur * 8192 + l31 * 128 +
                                         ((dc * 32 + hi * 16) ^ swz));
            bf16x8 k1 = *(const bf16x8*)(KsB + cur * 8192 + (32 + l31) * 128 +
                                         ((dc * 32 + hi * 16) ^ swz));
            s0 = __builtin_amdgcn_mfma_f32_32x32x16_bf16(k0, qf[dc], s0, 0, 0, 0);
            s1 = __builtin_amdgcn_mfma_f32_32x32x16_bf16(k1, qf[dc], s1, 0, 0, 0);
        }
        __builtin_amdgcn_s_setprio(0);

        // ---- max-free softmax: p = exp2(s); l += sum(p)
#pragma unroll
        for (int r = 0; r < 16; ++r) s0[r] = __builtin_amdgcn_exp2f(s0[r]);
#pragma unroll
        for (int r = 0; r < 16; ++r) s1[r] = __builtin_amdgcn_exp2f(s1[r]);
        float a8[8];
#pragma unroll
        for (int r = 0; r < 8; ++r)
            a8[r] = (s0[r] + s0[r + 8]) + (s1[r] + s1[r + 8]);
        float rs = ((a8[0] + a8[1]) + (a8[2] + a8[3])) +
                   ((a8[4] + a8[5]) + (a8[6] + a8[7]));
        rs += __shfl_xor(rs, 32);             // cross-half combine
        l_run += rs;

        // ---- P exchange (permlane32_swap, distinct operands) + PV
        __builtin_amdgcn_s_setprio(1);
#pragma unroll
        for (int s = 0; s < 4; ++s) {
            const int base = 8 * (s & 1);
            f32x16& P = (s < 2) ? s0 : s1;
            u32 a0 = pack2(P[base + 0], P[base + 1]);
            u32 a1 = pack2(P[base + 2], P[base + 3]);
            u32 b0 = pack2(P[base + 4], P[base + 5]);
            u32 b1 = pack2(P[base + 6], P[base + 7]);
            asm("v_permlane32_swap_b32 %0, %1" : "+v"(a0), "+v"(b0));
            asm("v_permlane32_swap_b32 %0, %1" : "+v"(a1), "+v"(b1));
            union { u32 u[4]; bf16x8 v; } pa;
            pa.u[0] = a0; pa.u[1] = a1; pa.u[2] = b0; pa.u[3] = b1;
            const bf16_t* vtb = VtB + cur * 4608;
            bf16x8 va0 = *(const bf16x8*)&vtb[l31 * 72 + s * 16 + hi * 8];
            bf16x8 va1 = *(const bf16x8*)&vtb[(32 + l31) * 72 + s * 16 + hi * 8];
            acc0 = __builtin_amdgcn_mfma_f32_32x32x16_bf16(va0, pa.v, acc0, 0, 0, 0);
            acc1 = __builtin_amdgcn_mfma_f32_32x32x16_bf16(va1, pa.v, acc1, 0, 0, 0);
        }
        __builtin_amdgcn_s_setprio(0);

        if (it + 1 < FNT) WRITE_V(cur ^ 1);
        __syncthreads();
    }

    // ---- epilogue
    bf16_t* sw = (bf16_t*)lds + wave * (32 * 72);
    float inv = 1.0f / l_run;
#pragma unroll
    for (int g = 0; g < 4; ++g) {
        bf16x4 w0, w1;
#pragma unroll
        for (int e = 0; e < 4; ++e) {
            w0[e] = (bf16_t)(acc0[4 * g + e] * inv);
            w1[e] = (bf16_t)(acc1[4 * g + e] * inv);
        }
        int d0 = 8 * g + 4 * hi;
        *(bf16x4*)&sw[l31 * 72 + d0] = w0;
        *(bf16x4*)&sw[l31 * 72 + 32 + d0] = w1;
    }
    __syncthreads();
    {
        int q = lane >> 1, half = lane & 1;
        const bf16_t* srow = sw + q * 72 + half * 32;
        int s = q0 + q;
        int b = bh >> 4, h = bh & 15;
        bf16_t* dst = AVb + ((size_t)s * BATCH + b) * DMODEL + h * HDIM + half * 32;
#pragma unroll
        for (int k = 0; k < 4; ++k)
            *(bf16x8*)(dst + k * 8) = *(const bf16x8*)(srow + k * 8);
    }
}

// ---------------------------------------------------------------------------
extern "C" void kernel_launch(void* const* d_in, const int* in_sizes, int n_in,
                              void* d_out, int out_size, void* d_ws, size_t ws_size,
                              hipStream_t stream)
{
    const float* X   = (const float*)d_in[0];
    const float* Wkv = (const float*)d_in[1];
    const float* bkv = (const float*)d_in[2];
    const float* Wq  = (const float*)d_in[3];
    const float* bq  = (const float*)d_in[4];
    const float* Wp  = (const float*)d_in[5];
    const float* bp  = (const float*)d_in[6];
    float* out = (float*)d_out;

    char* ws = (char*)d_ws;
    size_t off = 0;
    auto alloc = [&](size_t bytes) -> void* {
        void* p = ws + off;
        off += (bytes + 255) & ~(size_t)255;
        return p;
    };
    bf16_t* WqkvT = (bf16_t*)alloc((size_t)3072 * 1024 * 2);  // [Wkv^T ; Wq^T]
    bf16_t* WpT   = (bf16_t*)alloc((size_t)1024 * 1024 * 2);
    bf16_t* Qb    = (bf16_t*)alloc((size_t)32 * S_LEN * HDIM * 2);
    bf16_t* Kb    = (bf16_t*)alloc((size_t)32 * S_LEN * HDIM * 2);
    bf16_t* Vb    = (bf16_t*)alloc((size_t)32 * S_LEN * HDIM * 2);
    bf16_t* Xbf   = (bf16_t*)alloc((size_t)4096 * 1024 * 2);
    bf16_t* AVb   = (bf16_t*)alloc((size_t)4096 * 1024 * 2);

    prep_kernel<<<3072, 256, 0, stream>>>(X, Xbf, Wkv, Wq, Wp, WqkvT, WpT);
    gemm_qkv<<<dim3(32, 24), 256, 0, stream>>>(Xbf, WqkvT, bkv, bq, Kb, Vb, Qb);
    flash_kernel<<<dim3(S_LEN / 128, 32), 256, 0, stream>>>(Qb, Kb, Vb, AVb);
    gemm_out_kernel<<<dim3(64, 8), 256, 0, stream>>>(AVb, WpT, bp, out);
}

// Round 15
// 121.280 us; speedup vs baseline: 1.0995x; 1.0117x over previous
//
#include <hip/hip_runtime.h>
#include <hip/hip_bf16.h>
#include <stdint.h>

// Fused attention block: S=2048, B=2, D=1024, H=16, HD=64.
// Round 15: R14 + (a) gemm_qkv transposed-acc epilogue (operand-swapped MFMA,
// LDS re-transpose, fully coalesced 128B bf16x8 stores instead of 64 scattered
// 32B-granular stores/thread) + (b) flash XCD-chunk block decode (R6-proven,
// FETCH 69.7->12.3MB).

typedef __bf16 bf16_t;
typedef __bf16 bf16x8 __attribute__((ext_vector_type(8)));
typedef __bf16 bf16x4 __attribute__((ext_vector_type(4)));
typedef __bf16 bf16x2 __attribute__((ext_vector_type(2)));
typedef float f32x4 __attribute__((ext_vector_type(4)));
typedef float f32x16 __attribute__((ext_vector_type(16)));
typedef uint32_t u32;

#define S_LEN 2048
#define BATCH 2
#define DMODEL 1024
#define NHEAD 16
#define HDIM 64
#define KVB 64
#define FNT (S_LEN / KVB)
// 0.125 (1/sqrt(64)) * log2(e), folded into Q so softmax uses exp2
#define Q_SCALE 0.1803368801111204f

__device__ inline void gld16(const void* g, void* l)
{
    __builtin_amdgcn_global_load_lds(
        (const __attribute__((address_space(1))) void*)g,
        (__attribute__((address_space(3))) void*)l, 16, 0, 0);
}

__device__ inline u32 pack2(float a, float b)
{
    union { bf16x2 h; u32 u; } c;
    c.h[0] = (bf16_t)a; c.h[1] = (bf16_t)b;
    return c.u;
}

// ---------------------------------------------------------------------------
// Fused prep: blocks [0,2048) = X f32->bf16; [2048,2560) = Wkv transpose;
// [2560,2816) = Wq transpose; [2816,3072) = Wp transpose.
// ---------------------------------------------------------------------------
__global__ __launch_bounds__(256) void prep_kernel(
    const float* __restrict__ X, bf16_t* __restrict__ Xbf,
    const float* __restrict__ Wkv, const float* __restrict__ Wq,
    const float* __restrict__ Wp, bf16_t* __restrict__ WqkvT,
    bf16_t* __restrict__ WpT)
{
    __shared__ float tile[64][65];
    int bid = blockIdx.x;
    if (bid < 2048) {
        size_t i = ((size_t)bid * 256 + threadIdx.x) * 8;
        float4 f0 = *(const float4*)(X + i);
        float4 f1 = *(const float4*)(X + i + 4);
        bf16x8 o;
        o[0] = (bf16_t)f0.x; o[1] = (bf16_t)f0.y;
        o[2] = (bf16_t)f0.z; o[3] = (bf16_t)f0.w;
        o[4] = (bf16_t)f1.x; o[5] = (bf16_t)f1.y;
        o[6] = (bf16_t)f1.z; o[7] = (bf16_t)f1.w;
        *(bf16x8*)(Xbf + i) = o;
        return;
    }
    const float* in;
    bf16_t* out;
    int N, n0, k0;
    const int K = 1024;
    if (bid < 2560) {
        int id = bid - 2048;            // 32 x 16
        in = Wkv; out = WqkvT; N = 2048;
        n0 = (id & 31) * 64; k0 = (id >> 5) * 64;
    } else if (bid < 2816) {
        int id = bid - 2560;            // 16 x 16
        in = Wq; out = WqkvT + (size_t)2048 * 1024; N = 1024;
        n0 = (id & 15) * 64; k0 = (id >> 4) * 64;
    } else {
        int id = bid - 2816;            // 16 x 16
        in = Wp; out = WpT; N = 1024;
        n0 = (id & 15) * 64; k0 = (id >> 4) * 64;
    }
    int r = threadIdx.x >> 2;
    int c = (threadIdx.x & 3) * 16;
    const float* src = in + (size_t)(k0 + r) * N + n0 + c;
#pragma unroll
    for (int j = 0; j < 16; j += 4) {
        float4 f = *(const float4*)(src + j);
        tile[r][c + j + 0] = f.x;
        tile[r][c + j + 1] = f.y;
        tile[r][c + j + 2] = f.z;
        tile[r][c + j + 3] = f.w;
    }
    __syncthreads();
    bf16x8 o0, o1;
#pragma unroll
    for (int j = 0; j < 8; ++j) o0[j] = (bf16_t)tile[c + j][r];
#pragma unroll
    for (int j = 0; j < 8; ++j) o1[j] = (bf16_t)tile[c + 8 + j][r];
    bf16_t* dst = out + (size_t)(n0 + r) * K + k0 + c;
    *(bf16x8*)dst = o0;
    *(bf16x8*)(dst + 8) = o1;
}

// ---------------------------------------------------------------------------
// Fused QKV GEMM, BK=64, XOR-swizzled gload_lds staging.
// MFMA operands SWAPPED vs R14: acc[mi][ni] holds C^T fragments, so each lane
// owns 4 consecutive n(d) of one m-row. Epilogue: per-wave LDS re-transpose
// ([64 m][72] bf16, conflict-free) -> 8 coalesced 128B bf16x8 stores/thread.
// ---------------------------------------------------------------------------
__global__ __launch_bounds__(256) void gemm_qkv(
    const bf16_t* __restrict__ A, const bf16_t* __restrict__ WT,
    const float* __restrict__ bkv, const float* __restrict__ bq,
    bf16_t* __restrict__ outK, bf16_t* __restrict__ outV,
    bf16_t* __restrict__ outQ)
{
    const int K = 1024;
    __shared__ __align__(16) char shmem[36864];  // 32KB staging | 4x9216 epi
    char* AsB = shmem;
    char* BsB = shmem + 16384;
    int tid = threadIdx.x;
    int wave = tid >> 6, lane = tid & 63;
    int l15 = lane & 15, l4 = lane >> 4;
    int m0 = blockIdx.x * 128, n0 = blockIdx.y * 128;
    int wr = (wave >> 1) * 64, wc = (wave & 1) * 64;

    char* ldsT = (wave < 2) ? AsB : BsB;
    const bf16_t* gbase = (wave < 2) ? A : WT;
    int rbase = (wave & 1) * 64;
    int tile0 = (wave < 2) ? m0 : n0;
    int srow = lane >> 3;
    int kcb = ((lane & 7) << 4) ^ (srow << 4);
    int rx = (l15 & 7) << 4;

    f32x4 acc[4][4] = {};

    for (int k0 = 0; k0 < K; k0 += 64) {
#pragma unroll
        for (int j = 0; j < 8; ++j) {
            const char* g = (const char*)(gbase +
                (size_t)(tile0 + rbase + j * 8 + srow) * K + k0) + kcb;
            gld16(g, ldsT + (rbase + j * 8) * 128);
        }
        __syncthreads();
#pragma unroll
        for (int kk = 0; kk < 2; ++kk) {
            int cb = (kk * 64 + l4 * 16) ^ rx;
            bf16x8 af[4], bfr[4];
#pragma unroll
            for (int i = 0; i < 4; ++i)
                af[i] = *(const bf16x8*)(AsB + (wr + i * 16 + l15) * 128 + cb);
#pragma unroll
            for (int i = 0; i < 4; ++i)
                bfr[i] = *(const bf16x8*)(BsB + (wc + i * 16 + l15) * 128 + cb);
#pragma unroll
            for (int mi = 0; mi < 4; ++mi)
#pragma unroll
                for (int ni = 0; ni < 4; ++ni)
                    // swapped: D[row=n][col=m] -> lane holds 4 consecutive n
                    acc[mi][ni] = __builtin_amdgcn_mfma_f32_16x16x32_bf16(
                        bfr[ni], af[mi], acc[mi][ni], 0, 0, 0);
        }
        __syncthreads();
    }

    // ---- epilogue: wave quadrant = rows [m0+wr,+64) x cols [cb0,+64)
    int cb0 = n0 + wc;                       // multiple of 64 -> one head
    int h = (cb0 & 1023) >> 6;
    bf16_t* dst;
    float qs = 1.0f;
    if (cb0 < 1024)       dst = outK;
    else if (cb0 < 2048)  dst = outV;
    else                { dst = outQ; qs = Q_SCALE; }
    const float* bb = (cb0 < 2048) ? (bkv + cb0) : (bq + cb0 - 2048);

    bf16_t* sw = (bf16_t*)(shmem + wave * 9216);   // [64 m][72] bf16
#pragma unroll
    for (int mi = 0; mi < 4; ++mi) {
#pragma unroll
        for (int ni = 0; ni < 4; ++ni) {
            float4 b4 = *(const float4*)&bb[ni * 16 + l4 * 4];
            bf16x4 w;
#pragma unroll
            for (int e = 0; e < 4; ++e)
                w[e] = (bf16_t)((acc[mi][ni][e] + ((const float*)&b4)[e]) * qs);
            *(bf16x4*)&sw[(mi * 16 + l15) * 72 + ni * 16 + l4 * 4] = w;
        }
    }
    // wave-private scratch: no barrier needed (compiler inserts lgkmcnt)
    int rsub = lane >> 3;          // 0..7
    int c8 = (lane & 7) * 8;       // element offset, 16B chunks
#pragma unroll
    for (int j = 0; j < 8; ++j) {
        int row = j * 8 + rsub;
        bf16x8 v = *(const bf16x8*)&sw[row * 72 + c8];
        int gm = m0 + wr + row;
        int s = gm >> 1, b = gm & 1;
        *(bf16x8*)&dst[((size_t)((b << 4) + h) * S_LEN + s) * HDIM + c8] = v;
    }
}

// ---------------------------------------------------------------------------
// Output projection GEMM, BK=64, XOR-swizzled staging (R12 verbatim).
// ---------------------------------------------------------------------------
__global__ __launch_bounds__(256) void gemm_out_kernel(
    const bf16_t* __restrict__ A, const bf16_t* __restrict__ WT,
    const float* __restrict__ bias, float* __restrict__ outF)
{
    const int K = 1024, N = 1024;
    __shared__ __align__(16) char AsB[64 * 128];
    __shared__ __align__(16) char BsB[128 * 128];
    int tid = threadIdx.x, wave = tid >> 6, lane = tid & 63;
    int l15 = lane & 15, l4 = lane >> 4;
    int m0 = blockIdx.x * 64, n0 = blockIdx.y * 128;
    int wc = wave * 32;
    int srow = lane >> 3;
    int kcb = ((lane & 7) << 4) ^ (srow << 4);
    int rx = (l15 & 7) << 4;

    f32x4 acc[4][2] = {};

    for (int k0 = 0; k0 < K; k0 += 64) {
#pragma unroll
        for (int j = 0; j < 6; ++j) {
            int slot = wave * 6 + j;
            const bf16_t* g;
            char* l;
            if (slot < 8) {
                g = A + (size_t)(m0 + slot * 8 + srow) * K + k0;
                l = AsB + slot * 1024;
            } else {
                g = WT + (size_t)(n0 + (slot - 8) * 8 + srow) * K + k0;
                l = BsB + (slot - 8) * 1024;
            }
            gld16((const char*)g + kcb, l);
        }
        __syncthreads();
#pragma unroll
        for (int kk = 0; kk < 2; ++kk) {
            int cb = (kk * 64 + l4 * 16) ^ rx;
            bf16x8 af[4], bfr[2];
#pragma unroll
            for (int i = 0; i < 4; ++i)
                af[i] = *(const bf16x8*)(AsB + (i * 16 + l15) * 128 + cb);
#pragma unroll
            for (int i = 0; i < 2; ++i)
                bfr[i] = *(const bf16x8*)(BsB + (wc + i * 16 + l15) * 128 + cb);
#pragma unroll
            for (int mi = 0; mi < 4; ++mi)
#pragma unroll
                for (int ni = 0; ni < 2; ++ni)
                    acc[mi][ni] = __builtin_amdgcn_mfma_f32_16x16x32_bf16(
                        af[mi], bfr[ni], acc[mi][ni], 0, 0, 0);
        }
        __syncthreads();
    }

#pragma unroll
    for (int mi = 0; mi < 4; ++mi)
#pragma unroll
        for (int ni = 0; ni < 2; ++ni)
#pragma unroll
            for (int e = 0; e < 4; ++e) {
                int gm = m0 + mi * 16 + l4 * 4 + e;
                int gn = n0 + wc + ni * 16 + l15;
                outF[(size_t)gm * N + gn] = acc[mi][ni][e] + bias[gn];
            }
}

// ---------------------------------------------------------------------------
// Flash attention (R12/R10 body) + XCD-chunk block decode (1-D grid 512).
// ---------------------------------------------------------------------------
__global__ __launch_bounds__(256) void flash_kernel(
    const bf16_t* __restrict__ Qb, const bf16_t* __restrict__ Kb,
    const bf16_t* __restrict__ Vb, bf16_t* __restrict__ AVb)
{
    __shared__ __align__(16) char lds[34816];
    char* KsB = lds;                         // 2 x [64][64] bf16, swizzled
    bf16_t* VtB = (bf16_t*)(lds + 16384);    // 2 x [64][72] bf16

    int bid = blockIdx.x;
    int id = (bid & 7) * 64 + (bid >> 3);    // XCD-chunked: 4 heads per XCD
    int bh = id >> 4;                        // 0..31
    int qx = id & 15;                        // 0..15
    int tid = threadIdx.x, wave = tid >> 6, lane = tid & 63;
    int l31 = lane & 31, hi = lane >> 5;

    const bf16_t* Qp = Qb + (size_t)bh * S_LEN * HDIM;
    const bf16_t* Kp = Kb + (size_t)bh * S_LEN * HDIM;
    const bf16_t* Vp = Vb + (size_t)bh * S_LEN * HDIM;

    int q0 = qx * 128 + wave * 32;

    bf16x8 qf[4];
#pragma unroll
    for (int dc = 0; dc < 4; ++dc)
        qf[dc] = *(const bf16x8*)(Qp + (size_t)(q0 + l31) * HDIM + dc * 16 + hi * 8);

    f32x16 acc0 = {}, acc1 = {};
    float l_run = 0.f;

    int krow = lane >> 3;
    int kcb = ((lane & 7) << 4) ^ (krow << 4);
    int vd = (tid >> 4) * 4;
    int vt = (tid & 15) * 2;
    bf16x4 vreg[2][2];
    int swz = (l31 & 7) << 4;

#define STAGE_K(it, buf)                                                       \
    {                                                                          \
        _Pragma("unroll")                                                      \
        for (int j = 0; j < 2; ++j) {                                          \
            int t = wave * 16 + j * 8 + krow;                                  \
            const char* g = (const char*)Kp +                                  \
                ((size_t)((it) * KVB + t) * HDIM) * 2 + kcb;                   \
            gld16(g, KsB + (buf) * 8192 + (wave * 16 + j * 8) * 128);          \
        }                                                                      \
    }
#define LOAD_V(it)                                                             \
    {                                                                          \
        const bf16_t* vb = Vp + (size_t)((it) * KVB + vt) * HDIM + vd;         \
        vreg[0][0] = *(const bf16x4*)vb;                                       \
        vreg[0][1] = *(const bf16x4*)(vb + HDIM);                              \
        vreg[1][0] = *(const bf16x4*)(vb + 32 * HDIM);                         \
        vreg[1][1] = *(const bf16x4*)(vb + 33 * HDIM);                         \
    }
#define WRITE_V(buf)                                                           \
    {                                                                          \
        bf16_t* vtb = VtB + (buf) * 4608;                                      \
        _Pragma("unroll")                                                      \
        for (int p = 0; p < 2; ++p) {                                          \
            _Pragma("unroll")                                                  \
            for (int j = 0; j < 4; ++j) {                                      \
                bf16x2 w;                                                      \
                w[0] = vreg[p][0][j];                                          \
                w[1] = vreg[p][1][j];                                          \
                *(bf16x2*)&vtb[(vd + j) * 72 + vt + 32 * p] = w;               \
            }                                                                  \
        }                                                                      \
    }

    STAGE_K(0, 0);
    LOAD_V(0);
    WRITE_V(0);
    __syncthreads();

    for (int it = 0; it < FNT; ++it) {
        int cur = it & 1;
        if (it + 1 < FNT) {
            STAGE_K(it + 1, cur ^ 1);
            LOAD_V(it + 1);
        }

        // ---- QK^T (S^T)
        f32x16 s0 = {}, s1 = {};
        __builtin_amdgcn_s_setprio(1);
#pragma unroll
        for (int dc = 0; dc < 4; ++dc) {
            bf16x8 k0 = *(const bf16x8*)(KsB + cur * 8192 + l31 * 128 +
                                         ((dc * 32 + hi * 16) ^ swz));
            bf16x8 k1 = *(const bf16x8*)(KsB + cur * 8192 + (32 + l31) * 128 +
                                         ((dc * 32 + hi * 16) ^ swz));
            s0 = __builtin_amdgcn_mfma_f32_32x32x16_bf16(k0, qf[dc], s0, 0, 0, 0);
            s1 = __builtin_amdgcn_mfma_f32_32x32x16_bf16(k1, qf[dc], s1, 0, 0, 0);
        }
        __builtin_amdgcn_s_setprio(0);

        // ---- max-free softmax: p = exp2(s); l += sum(p)
#pragma unroll
        for (int r = 0; r < 16; ++r) s0[r] = __builtin_amdgcn_exp2f(s0[r]);
#pragma unroll
        for (int r = 0; r < 16; ++r) s1[r] = __builtin_amdgcn_exp2f(s1[r]);
        float a8[8];
#pragma unroll
        for (int r = 0; r < 8; ++r)
            a8[r] = (s0[r] + s0[r + 8]) + (s1[r] + s1[r + 8]);
        float rs = ((a8[0] + a8[1]) + (a8[2] + a8[3])) +
                   ((a8[4] + a8[5]) + (a8[6] + a8[7]));
        rs += __shfl_xor(rs, 32);             // cross-half combine
        l_run += rs;

        // ---- P exchange (permlane32_swap, distinct operands) + PV
        __builtin_amdgcn_s_setprio(1);
#pragma unroll
        for (int s = 0; s < 4; ++s) {
            const int base = 8 * (s & 1);
            f32x16& P = (s < 2) ? s0 : s1;
            u32 a0 = pack2(P[base + 0], P[base + 1]);
            u32 a1 = pack2(P[base + 2], P[base + 3]);
            u32 b0 = pack2(P[base + 4], P[base + 5]);
            u32 b1 = pack2(P[base + 6], P[base + 7]);
            asm("v_permlane32_swap_b32 %0, %1" : "+v"(a0), "+v"(b0));
            asm("v_permlane32_swap_b32 %0, %1" : "+v"(a1), "+v"(b1));
            union { u32 u[4]; bf16x8 v; } pa;
            pa.u[0] = a0; pa.u[1] = a1; pa.u[2] = b0; pa.u[3] = b1;
            const bf16_t* vtb = VtB + cur * 4608;
            bf16x8 va0 = *(const bf16x8*)&vtb[l31 * 72 + s * 16 + hi * 8];
            bf16x8 va1 = *(const bf16x8*)&vtb[(32 + l31) * 72 + s * 16 + hi * 8];
            acc0 = __builtin_amdgcn_mfma_f32_32x32x16_bf16(va0, pa.v, acc0, 0, 0, 0);
            acc1 = __builtin_amdgcn_mfma_f32_32x32x16_bf16(va1, pa.v, acc1, 0, 0, 0);
        }
        __builtin_amdgcn_s_setprio(0);

        if (it + 1 < FNT) WRITE_V(cur ^ 1);
        __syncthreads();
    }

    // ---- epilogue
    bf16_t* sw = (bf16_t*)lds + wave * (32 * 72);
    float inv = 1.0f / l_run;
#pragma unroll
    for (int g = 0; g < 4; ++g) {
        bf16x4 w0, w1;
#pragma unroll
        for (int e = 0; e < 4; ++e) {
            w0[e] = (bf16_t)(acc0[4 * g + e] * inv);
            w1[e] = (bf16_t)(acc1[4 * g + e] * inv);
        }
        int d0 = 8 * g + 4 * hi;
        *(bf16x4*)&sw[l31 * 72 + d0] = w0;
        *(bf16x4*)&sw[l31 * 72 + 32 + d0] = w1;
    }
    __syncthreads();
    {
        int q = lane >> 1, half = lane & 1;
        const bf16_t* srow = sw + q * 72 + half * 32;
        int s = q0 + q;
        int b = bh >> 4, h = bh & 15;
        bf16_t* dst = AVb + ((size_t)s * BATCH + b) * DMODEL + h * HDIM + half * 32;
#pragma unroll
        for (int k = 0; k < 4; ++k)
            *(bf16x8*)(dst + k * 8) = *(const bf16x8*)(srow + k * 8);
    }
}

// ---------------------------------------------------------------------------
extern "C" void kernel_launch(void* const* d_in, const int* in_sizes, int n_in,
                              void* d_out, int out_size, void* d_ws, size_t ws_size,
                              hipStream_t stream)
{
    const float* X   = (const float*)d_in[0];
    const float* Wkv = (const float*)d_in[1];
    const float* bkv = (const float*)d_in[2];
    const float* Wq  = (const float*)d_in[3];
    const float* bq  = (const float*)d_in[4];
    const float* Wp  = (const float*)d_in[5];
    const float* bp  = (const float*)d_in[6];
    float* out = (float*)d_out;

    char* ws = (char*)d_ws;
    size_t off = 0;
    auto alloc = [&](size_t bytes) -> void* {
        void* p = ws + off;
        off += (bytes + 255) & ~(size_t)255;
        return p;
    };
    bf16_t* WqkvT = (bf16_t*)alloc((size_t)3072 * 1024 * 2);  // [Wkv^T ; Wq^T]
    bf16_t* WpT   = (bf16_t*)alloc((size_t)1024 * 1024 * 2);
    bf16_t* Qb    = (bf16_t*)alloc((size_t)32 * S_LEN * HDIM * 2);
    bf16_t* Kb    = (bf16_t*)alloc((size_t)32 * S_LEN * HDIM * 2);
    bf16_t* Vb    = (bf16_t*)alloc((size_t)32 * S_LEN * HDIM * 2);
    bf16_t* Xbf   = (bf16_t*)alloc((size_t)4096 * 1024 * 2);
    bf16_t* AVb   = (bf16_t*)alloc((size_t)4096 * 1024 * 2);

    prep_kernel<<<3072, 256, 0, stream>>>(X, Xbf, Wkv, Wq, Wp, WqkvT, WpT);
    gemm_qkv<<<dim3(32, 24), 256, 0, stream>>>(Xbf, WqkvT, bkv, bq, Kb, Vb, Qb);
    flash_kernel<<<512, 256, 0, stream>>>(Qb, Kb, Vb, AVb);
    gemm_out_kernel<<<dim3(64, 8), 256, 0, stream>>>(AVb, WpT, bp, out);
}